// Round 4
// baseline (442.005 us; speedup 1.0000x reference)
//
#include <hip/hip_runtime.h>
#include <hip/hip_fp16.h>

// Problem constants
constexpr int B_N = 4;
constexpr int C_N = 3;
constexpr int H_IMG = 720;
constexpr int W_IMG = 1280;
constexpr int HW = H_IMG * W_IMG;
// KERNEL_RADIUS=4, KERNEL_SIGMA2=0.5 -> w = exp(-d2)

// Gather tiling: block owns 64x64 targets; thread owns 8x (x) * 2 (y) targets.
constexpr int TW = 64, TH = 64;
constexpr int HALO = 7;                 // R(4) + flow slack (3.5, rounded)
constexpr int CW = TW + 2 * HALO;       // 78
constexpr int CH = TH + 2 * HALO;       // 78
constexpr int PITCH = 79;               // odd pitch
constexpr int PLANE = CH * PITCH;       // 6162
constexpr float FLOW_MAX = 3.5f;        // outlier threshold (halo slack)
constexpr float LOG2E = 1.44269504f;
constexpr float MARKER = 30.0f;         // E underflows to 0; G stays finite

// e^{-1}, e^{-3}, e^{-5}, e^{-7} for the G^delta chain
#define K1 0.36787944117144233f
#define K3 0.049787068367863944f
#define K5 0.006737946999085467f
#define K7 0.0009118819655545162f

__global__ __launch_bounds__(256, 2)
void gather_kernel(const float* __restrict__ src, const float* __restrict__ flow,
                   float* __restrict__ out) {
    __shared__ __half2 UV[PLANE];     // (u, v)
    __shared__ __half2 S01[PLANE];    // (s0, s1)
    __shared__ __half  S2[PLANE];     // s2
    // total 61.62 KB -> 2 blocks/CU

    const int b = blockIdx.z;
    const int tx0 = blockIdx.x * TW;
    const int ty0 = blockIdx.y * TH;
    const int cx0 = tx0 - HALO, cy0 = ty0 - HALO;

    const float* __restrict__ up = flow + (size_t)(b * 2) * HW;
    const float* __restrict__ vp = up + HW;
    const float* __restrict__ sp = src + (size_t)(b * 3) * HW;

    // Stage coverage. Invalid / outlier cells get u=v=MARKER (weights == 0,
    // all intermediates finite -> branchless main loop is NaN-safe).
    for (int idx = threadIdx.x; idx < CH * CW; idx += 256) {
        const int cr = idx / CW, cx = idx - cr * CW;
        const int gx = cx0 + cx, gy = cy0 + cr;
        float u = MARKER, v = MARKER, s0 = 0.f, s1 = 0.f, s2 = 0.f;
        if (gx >= 0 && gx < W_IMG && gy >= 0 && gy < H_IMG) {
            const int g = gy * W_IMG + gx;
            const float uu = up[g], vv = vp[g];
            if (fabsf(uu) <= FLOW_MAX && fabsf(vv) <= FLOW_MAX) {
                u = uu; v = vv;
                s0 = sp[g]; s1 = sp[HW + g]; s2 = sp[2 * HW + g];
            }
        }
        const int l = cr * PITCH + cx;
        UV[l] = __floats2half2_rn(u, v);
        S01[l] = __floats2half2_rn(s0, s1);
        S2[l] = __float2half_rn(s2);
    }
    __syncthreads();

    const int xg = threadIdx.x & 7;     // 8 x-groups of 8 targets
    const int yg = threadIdx.x >> 3;    // 32 row-pairs
    const int ty_a = ty0 + 2 * yg;      // target rows ty_a, ty_a+1

    float aW[2][8], a0[2][8], a1[2][8], a2[2][8];
#pragma unroll
    for (int j = 0; j < 2; ++j)
#pragma unroll
        for (int i = 0; i < 8; ++i) { aW[j][i] = 0.f; a0[j][i] = 0.f;
                                      a1[j][i] = 0.f; a2[j][i] = 0.f; }

    // Source rows sy in [ty_a-7, ty_a+8]; cols sx in [gx0-7, gx0+14].
    for (int oy = 0; oy < 16; ++oy) {
        const float Cy = (float)(oy - 7);               // dy = v + Cy (row a)
        const int lrow = (2 * yg + oy) * PITCH + 8 * xg;
#pragma unroll
        for (int ox = 0; ox < 22; ++ox) {
            const int l = lrow + ox;
            const float2 uv = __half22float2(UV[l]);
            const float2 s01 = __half22float2(S01[l]);
            const float s2v = __half2float(S2[l]);

            // dx relative to target i=4 (gx0+4): dx = u + (ox - 11)
            const float dx = uv.x + (float)(ox - 11);
            const float dy = uv.y + Cy;

            const float aL = dx * LOG2E;
            const float tX = aL * dx;
            const float E  = __builtin_amdgcn_exp2f(-tX);   // exp(-dx^2)
            const float g  = aL + aL;
            const float G  = __builtin_amdgcn_exp2f(g);     // exp(2dx)
            const float Gi = __builtin_amdgcn_exp2f(-g);    // exp(-2dx)

            const float bL = dy * LOG2E;
            const float tY = bL * dy;
            const float eya = __builtin_amdgcn_exp2f(-tY);  // exp(-dy^2)
            const float gy = bL + bL;
            const float Gy = __builtin_amdgcn_exp2f(gy);    // exp(2dy)
            const float rk = Gy * K1;                       // ey_b = ey_a*rk

            const float m1 = G * K1, m3 = G * K3, m5 = G * K5;
            const float n1 = Gi * K1, n3 = Gi * K3, n5 = Gi * K5, n7 = Gi * K7;
            float w[8];
            w[4] = E;
            w[5] = w[4] * m1; w[6] = w[5] * m3; w[7] = w[6] * m5;
            w[3] = w[4] * n1; w[2] = w[3] * n3; w[1] = w[2] * n5; w[0] = w[1] * n7;

            const float zw0 = eya,        zw1 = eya * rk;
            const float z00 = s01.x * eya, z01 = z00 * rk;
            const float z10 = s01.y * eya, z11 = z10 * rk;
            const float z20 = s2v * eya,   z21 = z20 * rk;

#pragma unroll
            for (int i = 0; i < 8; ++i) {
                aW[0][i] = fmaf(w[i], zw0, aW[0][i]);
                aW[1][i] = fmaf(w[i], zw1, aW[1][i]);
                a0[0][i] = fmaf(w[i], z00, a0[0][i]);
                a0[1][i] = fmaf(w[i], z01, a0[1][i]);
                a1[0][i] = fmaf(w[i], z10, a1[0][i]);
                a1[1][i] = fmaf(w[i], z11, a1[1][i]);
                a2[0][i] = fmaf(w[i], z20, a2[0][i]);
                a2[1][i] = fmaf(w[i], z21, a2[1][i]);
            }
        }
    }

    // Write raw accumulators; outlier scatter adds, finalize divides.
    float* __restrict__ wI = out;
    float* __restrict__ wb = out + (size_t)B_N * C_N * HW;
    const int gx0 = tx0 + 8 * xg;
#pragma unroll
    for (int j = 0; j < 2; ++j) {
        const int ty = ty_a + j;
        if (ty >= H_IMG) continue;
        const int tb = ty * W_IMG + gx0;              // 16B-aligned
        float* p0 = wI + (size_t)(b * 3 + 0) * HW + tb;
        float* p1 = wI + (size_t)(b * 3 + 1) * HW + tb;
        float* p2 = wI + (size_t)(b * 3 + 2) * HW + tb;
        float* pw = wb + (size_t)b * HW + tb;
        *(float4*)(p0)     = make_float4(a0[j][0], a0[j][1], a0[j][2], a0[j][3]);
        *(float4*)(p0 + 4) = make_float4(a0[j][4], a0[j][5], a0[j][6], a0[j][7]);
        *(float4*)(p1)     = make_float4(a1[j][0], a1[j][1], a1[j][2], a1[j][3]);
        *(float4*)(p1 + 4) = make_float4(a1[j][4], a1[j][5], a1[j][6], a1[j][7]);
        *(float4*)(p2)     = make_float4(a2[j][0], a2[j][1], a2[j][2], a2[j][3]);
        *(float4*)(p2 + 4) = make_float4(a2[j][4], a2[j][5], a2[j][6], a2[j][7]);
        *(float4*)(pw)     = make_float4(aW[j][0], aW[j][1], aW[j][2], aW[j][3]);
        *(float4*)(pw + 4) = make_float4(aW[j][4], aW[j][5], aW[j][6], aW[j][7]);
    }
}

// Exact splat for rare sources with |u|>3.5 or |v|>3.5 (~9.3e-4 of pixels).
__global__ __launch_bounds__(256)
void outlier_kernel(const float* __restrict__ src, const float* __restrict__ flow,
                    float* __restrict__ out) {
    const int n4 = B_N * HW / 4;
    const int i4 = blockIdx.x * 256 + threadIdx.x;
    if (i4 >= n4) return;
    const int per_b = HW / 4;
    const int b = i4 / per_b;
    const int g0 = (i4 - b * per_b) * 4;
    const float* __restrict__ up = flow + (size_t)(b * 2) * HW;
    const float4 u4 = *(const float4*)(up + g0);
    const float4 v4 = *(const float4*)(up + HW + g0);
    const float um = fmaxf(fmaxf(fabsf(u4.x), fabsf(u4.y)), fmaxf(fabsf(u4.z), fabsf(u4.w)));
    const float vm = fmaxf(fmaxf(fabsf(v4.x), fabsf(v4.y)), fmaxf(fabsf(v4.z), fabsf(v4.w)));
    if (um <= FLOW_MAX && vm <= FLOW_MAX) return;

    const float uu[4] = {u4.x, u4.y, u4.z, u4.w};
    const float vv[4] = {v4.x, v4.y, v4.z, v4.w};
    const float* __restrict__ sp = src + (size_t)(b * 3) * HW;
    float* __restrict__ wI = out;
    float* __restrict__ wb = out + (size_t)B_N * C_N * HW;

    for (int k = 0; k < 4; ++k) {
        const float u = uu[k], v = vv[k];
        if (fabsf(u) <= FLOW_MAX && fabsf(v) <= FLOW_MAX) continue;
        const int g = g0 + k;
        const int x = g % W_IMG, y = g / W_IMG;
        const float px = (float)x + u, py = (float)y + v;
        if (!(px > -6.f && px < (float)W_IMG + 5.f &&
              py > -6.f && py < (float)H_IMG + 5.f)) continue;

        const float bxf = floorf(px), byf = floorf(py);
        const int bx = (int)bxf, by = (int)byf;
        const float s0 = sp[g], s1 = sp[HW + g], s2 = sp[2 * HW + g];

        for (int dyi = -4; dyi <= 4; ++dyi) {
            const int tyy = by + dyi;
            if (tyy < 0 || tyy >= H_IMG) continue;
            const float dyf = (byf + (float)dyi) - py;
            const float dy2 = dyf * dyf;
            for (int dxi = -4; dxi <= 4; ++dxi) {
                const int txx = bx + dxi;
                if (txx < 0 || txx >= W_IMG) continue;
                const float dxf = (bxf + (float)dxi) - px;
                const float d2 = fmaf(dxf, dxf, dy2);
                if (d2 > 16.f) continue;
                const float w = __expf(-d2);
                const int t = tyy * W_IMG + txx;
                atomicAdd(&wb[(size_t)b * HW + t], w);
                atomicAdd(&wI[(size_t)(b * 3 + 0) * HW + t], w * s0);
                atomicAdd(&wI[(size_t)(b * 3 + 1) * HW + t], w * s1);
                atomicAdd(&wI[(size_t)(b * 3 + 2) * HW + t], w * s2);
            }
        }
    }
}

__global__ __launch_bounds__(256)
void finalize_kernel(float* __restrict__ out) {
    const int i = blockIdx.x * blockDim.x + threadIdx.x;
    const int n4 = B_N * HW / 4;
    if (i >= n4) return;
    const int per_b = HW / 4;
    const int b = i / per_b;
    const int hw = (i - b * per_b) * 4;
    float* __restrict__ wb = out + (size_t)B_N * C_N * HW + (size_t)b * HW + hw;
    float4 w = *(float4*)wb;
    const float4 inv = make_float4(1.f / (w.x + 1e-8f), 1.f / (w.y + 1e-8f),
                                   1.f / (w.z + 1e-8f), 1.f / (w.w + 1e-8f));
    float* base = out + (size_t)(b * 3) * HW + hw;
#pragma unroll
    for (int c = 0; c < 3; ++c) {
        float4 t = *(float4*)(base + (size_t)c * HW);
        t.x *= inv.x; t.y *= inv.y; t.z *= inv.z; t.w *= inv.w;
        *(float4*)(base + (size_t)c * HW) = t;
    }
    *(float4*)wb = make_float4(w.x > 0.f ? 1.f : 0.f, w.y > 0.f ? 1.f : 0.f,
                               w.z > 0.f ? 1.f : 0.f, w.w > 0.f ? 1.f : 0.f);
}

extern "C" void kernel_launch(void* const* d_in, const int* in_sizes, int n_in,
                              void* d_out, int out_size, void* d_ws, size_t ws_size,
                              hipStream_t stream) {
    const float* src = (const float*)d_in[0];    // (4,3,720,1280) fp32
    const float* flow = (const float*)d_in[1];   // (4,2,720,1280) fp32
    float* out = (float*)d_out;                  // img (4,3,HW) ++ mask (4,1,HW)

    dim3 grid(W_IMG / TW, (H_IMG + TH - 1) / TH, B_N);   // 20 x 12 x 4
    gather_kernel<<<grid, 256, 0, stream>>>(src, flow, out);

    const int n4 = B_N * HW / 4;
    outlier_kernel<<<(n4 + 255) / 256, 256, 0, stream>>>(src, flow, out);
    finalize_kernel<<<(n4 + 255) / 256, 256, 0, stream>>>(out);
}